// Round 5
// baseline (372.036 us; speedup 1.0000x reference)
//
#include <hip/hip_runtime.h>

// may_alias types for all LDS/global reinterpret accesses (defensive, zero-cost)
typedef __bf16 bf16v8 __attribute__((ext_vector_type(8)));
typedef bf16v8 bf16x8 __attribute__((may_alias));
typedef unsigned int u32v2 __attribute__((ext_vector_type(2)));
typedef u32v2 u32x2 __attribute__((may_alias));
typedef unsigned short u16v8 __attribute__((ext_vector_type(8)));
typedef u16v8 u16x8 __attribute__((may_alias));
typedef unsigned short u16v;
typedef u16v u16 __attribute__((may_alias));
typedef float f32x4 __attribute__((ext_vector_type(4)));
typedef unsigned int u32;

#define MEMFENCE() asm volatile("" ::: "memory")

union B8 { u32 u[4]; bf16v8 v; };

__device__ __forceinline__ u32 cvtpk(float lo, float hi) {
    u32 r;
    asm("v_cvt_pk_bf16_f32 %0, %1, %2" : "=v"(r) : "v"(lo), "v"(hi));
    return r;
}

__device__ __forceinline__ unsigned short f2b(float f) {
    union { float f; unsigned u; } a; a.f = f;
    unsigned r = a.u + 0x7FFFu + ((a.u >> 16) & 1u);   // RNE
    return (unsigned short)(r >> 16);
}

// ---- weight prep (R1-verbatim): wt[768][256] bf16 = [Wq|Wkv_K|Wkv_V]^T, wpt = Wp^T,
// b_all[768] = [bq|bkv]  (no scale baked; softmax applies 1/sqrt(dh))
__global__ void prep_weights(const float* __restrict__ Wq,
                             const float* __restrict__ Wkv,
                             const float* __restrict__ Wp,
                             const float* __restrict__ bq,
                             const float* __restrict__ bkv,
                             u16* __restrict__ wt,
                             u16* __restrict__ wpt,
                             float* __restrict__ b_all)
{
    int idx = blockIdx.x * 256 + threadIdx.x;
    if (idx < 196608) {                       // 768*256
        int c = idx >> 8, k = idx & 255;
        float v = (c < 256) ? Wq[k * 256 + c] : Wkv[k * 512 + (c - 256)];
        wt[idx] = f2b(v);
    } else if (idx < 262144) {                // + 256*256
        int j = idx - 196608;
        int c = j >> 8, k = j & 255;
        wpt[j] = f2b(Wp[k * 256 + c]);
    } else if (idx < 262912) {                // + 768 biases
        int i = idx - 262144;
        b_all[i] = (i < 256) ? bq[i] : bkv[i - 256];
    }
}

// R1-validated structure. Deltas from R1: single-pass QKV (numerically identical MFMA
// sequences, K/V parked via cvtpk), XCD-aware bid remap, tj-inner epilogue stores.
// LDS map (64 KiB, R1-verbatim): region X [0,32768): xs[64][256] -> vt chunks -> O_lds;
// region Y [32768,65536): per-wave chunk (Q -> K -> P). Swizzle: byte ^= (row&7)<<4.
__global__ __launch_bounds__(256, 2)
void fused_win_attn(const float* __restrict__ x,
                    const float* __restrict__ mask,
                    const u16* __restrict__ wt,
                    const u16* __restrict__ wpt,
                    const float* __restrict__ b_all,
                    const float* __restrict__ bp,
                    float* __restrict__ out)
{
    __shared__ __align__(16) unsigned char smem[65536];
    const int bid = blockIdx.x;
    // XCD remap (bijective): 8 batch-copies of one window share bid%8 -> same XCD L2.
    const int wdw   = (bid & 7) | ((bid >> 6) << 3);
    const int batch = (bid >> 3) & 7;
    const int b     = batch * 256 + wdw;

    const int tid = threadIdx.x;
    const int w   = tid >> 6;
    const int l   = tid & 63;
    const int lr  = l & 15;
    const int lg  = l >> 4;
    const int chunkoff = 32768 + w * 8192;
    const int vtoff    = w * 8192;
    const int wcol     = w * 64;
    const float scale = 0.17677669529663687f;   // 1/sqrt(32)

    f32x4 zero = {0.f, 0.f, 0.f, 0.f};

    // ---------- Phase 1 (R1-verbatim): stage x -> xs bf16 (swizzled) ----------
    {
        const float* xb = x + (size_t)b * 16384;
#pragma unroll
        for (int it = 0; it < 8; ++it) {
            int g   = it * 256 + tid;           // 8-float group id
            int row = g >> 5;
            int cg  = g & 31;
            const float4 f0 = *(const float4*)(xb + row * 256 + cg * 8);
            const float4 f1 = *(const float4*)(xb + row * 256 + cg * 8 + 4);
            u16v8 t;
            t[0] = f2b(f0.x); t[1] = f2b(f0.y); t[2] = f2b(f0.z); t[3] = f2b(f0.w);
            t[4] = f2b(f1.x); t[5] = f2b(f1.y); t[6] = f2b(f1.z); t[7] = f2b(f1.w);
            int off = row * 512 + ((cg * 16) ^ ((row & 7) << 4));
            *(u16x8*)(smem + off) = t;
        }
    }
    __syncthreads();   // #1

    // ---------- Phase 2: single-pass QKV (hf-split; park K,V packed) ----------
    u32 pkK[2][2][4][2], pkV[2][2][4][2];   // [hf][t][tj][epair]
#pragma unroll
    for (int hf = 0; hf < 2; ++hf) {
        f32x4 qa[2][4], ka[2][4], va[2][4];
#pragma unroll
        for (int t = 0; t < 2; ++t)
#pragma unroll
            for (int tj = 0; tj < 4; ++tj) { qa[t][tj] = zero; ka[t][tj] = zero; va[t][tj] = zero; }
#pragma unroll
        for (int ks = 0; ks < 8; ++ks) {
            bf16v8 af[2];
#pragma unroll
            for (int t = 0; t < 2; ++t) {
                int row = hf * 32 + t * 16 + lr;
                af[t] = *(const bf16x8*)(smem + row * 512 + ((ks * 64 + lg * 16) ^ ((row & 7) << 4)));
            }
#pragma unroll
            for (int tj = 0; tj < 4; ++tj) {
                const u16* wp0 = wt + (size_t)(wcol + tj * 16 + lr) * 256 + ks * 32 + lg * 8;
                bf16v8 bwq = *(const bf16x8*)(wp0);
                bf16v8 bwk = *(const bf16x8*)(wp0 + 256 * 256);
                bf16v8 bwv = *(const bf16x8*)(wp0 + 512 * 256);
#pragma unroll
                for (int t = 0; t < 2; ++t) {
                    qa[t][tj] = __builtin_amdgcn_mfma_f32_16x16x32_bf16(af[t], bwq, qa[t][tj], 0, 0, 0);
                    ka[t][tj] = __builtin_amdgcn_mfma_f32_16x16x32_bf16(af[t], bwk, ka[t][tj], 0, 0, 0);
                    va[t][tj] = __builtin_amdgcn_mfma_f32_16x16x32_bf16(af[t], bwv, va[t][tj], 0, 0, 0);
                }
            }
        }
        // stage Q half (R1 formula, scalar u16); park K,V (+bias) packed
#pragma unroll
        for (int tj = 0; tj < 4; ++tj) {
            float bqv = b_all[wcol + tj * 16 + lr];
            float bkr = b_all[256 + wcol + tj * 16 + lr];
            float bvr = b_all[512 + wcol + tj * 16 + lr];
            int col2 = (tj * 16 + lr) * 2;
#pragma unroll
            for (int t = 0; t < 2; ++t) {
#pragma unroll
                for (int e = 0; e < 4; ++e) {
                    int tok = hf * 32 + t * 16 + lg * 4 + e;
                    *(u16*)(smem + chunkoff + tok * 128 + (col2 ^ ((tok & 7) << 4)))
                        = f2b(qa[t][tj][e] + bqv);
                }
                pkK[hf][t][tj][0] = cvtpk(ka[t][tj][0] + bkr, ka[t][tj][1] + bkr);
                pkK[hf][t][tj][1] = cvtpk(ka[t][tj][2] + bkr, ka[t][tj][3] + bkr);
                pkV[hf][t][tj][0] = cvtpk(va[t][tj][0] + bvr, va[t][tj][1] + bvr);
                pkV[hf][t][tj][1] = cvtpk(va[t][tj][2] + bvr, va[t][tj][3] + bvr);
            }
        }
    }

    MEMFENCE();
    // read Q A-frags for S (R1 formula)
    bf16v8 aq[2][4];
#pragma unroll
    for (int hl = 0; hl < 2; ++hl)
#pragma unroll
        for (int ti = 0; ti < 4; ++ti) {
            int row = ti * 16 + lr;
            aq[hl][ti] = *(const bf16x8*)(smem + chunkoff + row * 128 +
                                          ((hl * 64 + lg * 16) ^ ((row & 7) << 4)));
        }
    MEMFENCE();

    // stage K into chunk (overwrite Q; R1 formula, scalar u16 from parked pairs)
#pragma unroll
    for (int hf = 0; hf < 2; ++hf)
#pragma unroll
        for (int t = 0; t < 2; ++t)
#pragma unroll
            for (int tj = 0; tj < 4; ++tj) {
                int col2 = (tj * 16 + lr) * 2;
#pragma unroll
                for (int ep = 0; ep < 2; ++ep) {
                    u32 u = pkK[hf][t][tj][ep];
                    int tok0 = hf * 32 + t * 16 + lg * 4 + ep * 2;
                    *(u16*)(smem + chunkoff + tok0 * 128 + (col2 ^ ((tok0 & 7) << 4))) = (unsigned short)u;
                    *(u16*)(smem + chunkoff + (tok0 + 1) * 128 + (col2 ^ (((tok0 + 1) & 7) << 4))) = (unsigned short)(u >> 16);
                }
            }

    __syncthreads();   // #2: xs fully consumed by all waves -> region X becomes vt chunks

    // stage V^T (R1 layout vt[c][n], packed b64)
#pragma unroll
    for (int hf = 0; hf < 2; ++hf)
#pragma unroll
        for (int t = 0; t < 2; ++t)
#pragma unroll
            for (int tj = 0; tj < 4; ++tj) {
                int c = tj * 16 + lr;
                int tok0 = hf * 32 + t * 16 + lg * 4;
                u32x2 pv2; pv2[0] = pkV[hf][t][tj][0]; pv2[1] = pkV[hf][t][tj][1];
                *(u32x2*)(smem + vtoff + c * 128 + ((tok0 * 2) ^ ((c & 7) << 4))) = pv2;
            }
    MEMFENCE();

    // ---------- Phase 3 (R1-verbatim): attention ----------
    f32x4 sH[2][4][4];
#pragma unroll
    for (int hl = 0; hl < 2; ++hl) {
        bf16v8 bk[4];
#pragma unroll
        for (int tj = 0; tj < 4; ++tj) {
            int n = tj * 16 + lr;
            bk[tj] = *(const bf16x8*)(smem + chunkoff + n * 128 +
                                      ((hl * 64 + lg * 16) ^ ((n & 7) << 4)));
        }
#pragma unroll
        for (int ti = 0; ti < 4; ++ti)
#pragma unroll
            for (int tj = 0; tj < 4; ++tj)
                sH[hl][ti][tj] = __builtin_amdgcn_mfma_f32_16x16x32_bf16(aq[hl][ti], bk[tj], zero, 0, 0, 0);
    }

    f32x4 oH[2][4][2];
    const float* mbase = mask + (size_t)wdw * 4096;
#pragma unroll
    for (int hl = 0; hl < 2; ++hl) {
        // scale + mask add
#pragma unroll
        for (int ti = 0; ti < 4; ++ti)
#pragma unroll
            for (int e = 0; e < 4; ++e) {
                int row = ti * 16 + lg * 4 + e;
#pragma unroll
                for (int tj = 0; tj < 4; ++tj)
                    sH[hl][ti][tj][e] = sH[hl][ti][tj][e] * scale + mbase[row * 64 + tj * 16 + lr];
            }
        // softmax (R1-verbatim shfl reduction)
        float inv[4][4];
#pragma unroll
        for (int ti = 0; ti < 4; ++ti)
#pragma unroll
            for (int e = 0; e < 4; ++e) {
                float v0 = sH[hl][ti][0][e], v1 = sH[hl][ti][1][e];
                float v2 = sH[hl][ti][2][e], v3 = sH[hl][ti][3][e];
                float m = fmaxf(fmaxf(v0, v1), fmaxf(v2, v3));
#pragma unroll
                for (int d = 1; d < 16; d <<= 1) m = fmaxf(m, __shfl_xor(m, d));
                v0 = __expf(v0 - m); v1 = __expf(v1 - m);
                v2 = __expf(v2 - m); v3 = __expf(v3 - m);
                float s = v0 + v1 + v2 + v3;
#pragma unroll
                for (int d = 1; d < 16; d <<= 1) s += __shfl_xor(s, d);
                inv[ti][e] = 1.0f / s;
                sH[hl][ti][0][e] = v0; sH[hl][ti][1][e] = v1;
                sH[hl][ti][2][e] = v2; sH[hl][ti][3][e] = v3;
            }
        // write unnormalized P into chunk (overwrites K; both heads' S already computed)
#pragma unroll
        for (int ti = 0; ti < 4; ++ti)
#pragma unroll
            for (int e = 0; e < 4; ++e) {
                int row = ti * 16 + lg * 4 + e;
#pragma unroll
                for (int tj = 0; tj < 4; ++tj)
                    *(u16*)(smem + chunkoff + row * 128 + ((((tj * 16 + lr) * 2)) ^ ((row & 7) << 4)))
                        = f2b(sH[hl][ti][tj][e]);
            }
        MEMFENCE();
        // PV (R1-verbatim)
#pragma unroll
        for (int ti = 0; ti < 4; ++ti)
#pragma unroll
            for (int tj = 0; tj < 2; ++tj) oH[hl][ti][tj] = zero;
#pragma unroll
        for (int kb = 0; kb < 2; ++kb) {
            bf16v8 ap[4], bv[2];
#pragma unroll
            for (int ti = 0; ti < 4; ++ti) {
                int row = ti * 16 + lr;
                ap[ti] = *(const bf16x8*)(smem + chunkoff + row * 128 +
                                          ((kb * 64 + lg * 16) ^ ((row & 7) << 4)));
            }
#pragma unroll
            for (int tj = 0; tj < 2; ++tj) {
                int c = hl * 32 + tj * 16 + lr;
                bv[tj] = *(const bf16x8*)(smem + vtoff + c * 128 +
                                          ((kb * 64 + lg * 16) ^ ((c & 7) << 4)));
            }
#pragma unroll
            for (int ti = 0; ti < 4; ++ti)
#pragma unroll
                for (int tj = 0; tj < 2; ++tj)
                    oH[hl][ti][tj] = __builtin_amdgcn_mfma_f32_16x16x32_bf16(ap[ti], bv[tj], oH[hl][ti][tj], 0, 0, 0);
        }
        MEMFENCE();
        // normalize O rows by 1/sum
#pragma unroll
        for (int ti = 0; ti < 4; ++ti)
#pragma unroll
            for (int tj = 0; tj < 2; ++tj)
#pragma unroll
                for (int e = 0; e < 4; ++e)
                    oH[hl][ti][tj][e] *= inv[ti][e];
    }

    __syncthreads();   // #3: all waves done reading vt chunks; region X becomes O_lds

    // ---------- Phase 4 (R1-verbatim): stage O -> O_lds[64][256] ----------
#pragma unroll
    for (int hl = 0; hl < 2; ++hl)
#pragma unroll
        for (int ti = 0; ti < 4; ++ti)
#pragma unroll
            for (int tj = 0; tj < 2; ++tj)
#pragma unroll
                for (int e = 0; e < 4; ++e) {
                    int row = ti * 16 + lg * 4 + e;
                    int cg  = (2 * w + hl) * 32 + tj * 16 + lr;
                    *(u16*)(smem + row * 512 + ((cg * 2) ^ ((row & 7) << 4)))
                        = f2b(oH[hl][ti][tj][e]);
                }
    __syncthreads();   // #4

    // ---------- Phase 5 (R1-verbatim): output projection ----------
    f32x4 pacc[4][4];
#pragma unroll
    for (int ti = 0; ti < 4; ++ti)
#pragma unroll
        for (int tj = 0; tj < 4; ++tj) pacc[ti][tj] = zero;
#pragma unroll
    for (int ks = 0; ks < 8; ++ks) {
        bf16v8 a_[4];
#pragma unroll
        for (int ti = 0; ti < 4; ++ti) {
            int row = ti * 16 + lr;
            a_[ti] = *(const bf16x8*)(smem + row * 512 + ((ks * 64 + lg * 16) ^ ((row & 7) << 4)));
        }
#pragma unroll
        for (int tj = 0; tj < 4; ++tj) {
            bf16v8 bw = *(const bf16x8*)(wpt + (size_t)(wcol + tj * 16 + lr) * 256 + ks * 32 + lg * 8);
#pragma unroll
            for (int ti = 0; ti < 4; ++ti)
                pacc[ti][tj] = __builtin_amdgcn_mfma_f32_16x16x32_bf16(a_[ti], bw, pacc[ti][tj], 0, 0, 0);
        }
    }
    // epilogue: + bp, store fp32; tj-INNER so each (ti,e) writes 256B contiguous spans
    float* ob = out + (size_t)b * 16384;
    float bpr[4];
#pragma unroll
    for (int tj = 0; tj < 4; ++tj) bpr[tj] = bp[wcol + tj * 16 + lr];
#pragma unroll
    for (int ti = 0; ti < 4; ++ti)
#pragma unroll
        for (int e = 0; e < 4; ++e) {
            int row = ti * 16 + lg * 4 + e;
            float* orow = ob + row * 256 + wcol;
#pragma unroll
            for (int tj = 0; tj < 4; ++tj)
                orow[tj * 16 + lr] = pacc[ti][tj][e] + bpr[tj];
        }
}

extern "C" void kernel_launch(void* const* d_in, const int* in_sizes, int n_in,
                              void* d_out, int out_size, void* d_ws, size_t ws_size,
                              hipStream_t stream) {
    const float* x    = (const float*)d_in[0];
    const float* mask = (const float*)d_in[1];
    const float* Wq   = (const float*)d_in[2];
    const float* bq   = (const float*)d_in[3];
    const float* Wkv  = (const float*)d_in[4];
    const float* bkv  = (const float*)d_in[5];
    const float* Wp   = (const float*)d_in[6];
    const float* bp   = (const float*)d_in[7];
    float* out = (float*)d_out;

    u16*   wt    = (u16*)d_ws;                 // 768*256 bf16
    u16*   wpt   = wt + 768 * 256;             // 256*256 bf16
    float* b_all = (float*)(wpt + 256 * 256);  // 768 f32

    prep_weights<<<1027, 256, 0, stream>>>(Wq, Wkv, Wp, bq, bkv, wt, wpt, b_all);
    fused_win_attn<<<2048, 256, 0, stream>>>(x, mask, wt, wpt, b_all, bp, out);
}